// Round 12
// baseline (1211.723 us; speedup 1.0000x reference)
//
#include <hip/hip_runtime.h>
#include <hip/hip_cooperative_groups.h>
#include <hip/hip_bf16.h>

namespace cg = cooperative_groups;

#define NNODES 10000
#define NEDGES 320000
#define ETOT   (NEDGES + NNODES)
#define NGRAPH 100
#define NCUS   256
#define CH     250   // HEADS*OUT
#define HOUT   125
#define MPAD   10048 // 157 * 64
#define NTILE  157   // MPAD/64
#define KP0    352   // layer-0 K=336 padded
#define KP1    256   // layers 1-3 K=250 padded
#define HPAD   256   // hb16 row stride (bf16)
#define DCAP   256   // per-node edge cache in LDS

typedef __attribute__((ext_vector_type(8))) short bf16x8;
typedef __attribute__((ext_vector_type(4))) float f32x4;

static __device__ __forceinline__ float bfbits2f(unsigned int u){
  union{ unsigned int i; float f; } v; v.i = u << 16; return v.f;
}
static __device__ __forceinline__ unsigned short f2bfbits(float f){
  __hip_bfloat16 b = __float2bfloat16(f);
  union{ __hip_bfloat16 b; unsigned short s; } v; v.b = b; return v.s;
}

struct MegaArgs {
  const float* x; const int* eidx; const int* batch;
  const float *W0,*W1,*W2,*W3;
  const float *as0,*ad0,*b0;
  const float *as1,*ad1,*b1;
  const float *as2,*ad2,*b2;
  const float *as3,*ad3,*b3;
  const float *lw1,*lb1,*lw2,*lb2,*lw3,*lb3,*lw4,*lb4;
  __hip_bfloat16 *hb16, *Abf0, *Abf, *Wt0, *Wt1, *Wt2, *Wt3;
  int *deg, *cursor, *rowptr, *csr_src, *gstart;
  float *esA,*edA,*esB,*edB;
  float* out;
};

// ---------------- scan: 256 threads, 1 block ----------------
__device__ void scan256(char* smemc, const int* __restrict__ deg, int* __restrict__ rowptr){
  const int CHUNK = 40;   // 256*40 = 10240 >= NNODES
  int tid = threadIdx.x;
  int base = tid * CHUNK;
  int sum = 0;
  #pragma unroll
  for (int u = 0; u < CHUNK; ++u){
    int i = base + u;
    sum += (i < NNODES) ? deg[i] : 0;
  }
  int lane = tid & 63, wv = tid >> 6;
  int v = sum;
  #pragma unroll
  for (int off = 1; off < 64; off <<= 1){
    int t = __shfl_up(v, off);
    if (lane >= off) v += t;
  }
  int* wtot = (int*)smemc;
  int* woff = (int*)(smemc + 64);
  if (lane == 63) wtot[wv] = v;
  __syncthreads();
  if (tid == 0){
    int acc = 0;
    #pragma unroll
    for (int w = 0; w < 4; ++w){ woff[w] = acc; acc += wtot[w]; }
  }
  __syncthreads();
  int run = woff[wv] + v - sum;
  #pragma unroll
  for (int u = 0; u < CHUNK; ++u){
    int i = base + u;
    if (i < NNODES){
      run += deg[i];
      rowptr[i+1] = run;
    }
  }
  if (tid == 0) rowptr[0] = 0;
}

// ---------------- MFMA GEMM tile + fused attention scores ----------------
__device__ __forceinline__ void gemm_body(int bx, int by,
    const __hip_bfloat16* __restrict__ A, const __hip_bfloat16* __restrict__ Wt,
    __hip_bfloat16* __restrict__ Cb, const float* __restrict__ asrc,
    const float* __restrict__ adst, float* __restrict__ esrc, float* __restrict__ edst,
    int Kp){
  int wv = threadIdx.x >> 6, lane = threadIdx.x & 63;
  int n16 = lane & 15, q = lane >> 4;
  int KC = Kp >> 5;
  int rowbase = bx * 64 + wv * 16;
  int bn = by * 64;
  int nt0 = bn >> 4;
  const __hip_bfloat16* ap = A  + (size_t)(rowbase + n16) * Kp + q * 8;
  const __hip_bfloat16* bp = Wt + ((size_t)nt0 * KC * 16 + n16) * 32 + q * 8;
  f32x4 ac0 = {0.f,0.f,0.f,0.f}, ac1 = ac0, ac2 = ac0, ac3 = ac0;
  for (int kc = 0; kc < KC; ++kc){
    bf16x8 a  = *(const bf16x8*)(ap + (size_t)kc * 32);
    bf16x8 b0 = *(const bf16x8*)(bp + ((size_t)0 * KC + kc) * 512);
    bf16x8 b1 = *(const bf16x8*)(bp + ((size_t)1 * KC + kc) * 512);
    bf16x8 b2 = *(const bf16x8*)(bp + ((size_t)2 * KC + kc) * 512);
    bf16x8 b3 = *(const bf16x8*)(bp + ((size_t)3 * KC + kc) * 512);
    ac0 = __builtin_amdgcn_mfma_f32_16x16x32_bf16(a, b0, ac0, 0, 0, 0);
    ac1 = __builtin_amdgcn_mfma_f32_16x16x32_bf16(a, b1, ac1, 0, 0, 0);
    ac2 = __builtin_amdgcn_mfma_f32_16x16x32_bf16(a, b2, ac2, 0, 0, 0);
    ac3 = __builtin_amdgcn_mfma_f32_16x16x32_bf16(a, b3, ac3, 0, 0, 0);
  }
  float es0[4] = {}, es1[4] = {}, ed0a[4] = {}, ed1a[4] = {};
  #define SCORE_T(AC, T) { \
    int col = bn + (T)*16 + n16; \
    bool ok = col < CH; \
    float av = ok ? asrc[col] : 0.f; \
    float dv = ok ? adst[col] : 0.f; \
    bool hh = col >= HOUT; \
    float av0 = hh ? 0.f : av, av1 = hh ? av : 0.f; \
    float dv0 = hh ? 0.f : dv, dv1 = hh ? dv : 0.f; \
    _Pragma("unroll") \
    for (int r = 0; r < 4; ++r){ \
      es0[r] += AC[r]*av0; es1[r] += AC[r]*av1; \
      ed0a[r] += AC[r]*dv0; ed1a[r] += AC[r]*dv1; } }
  SCORE_T(ac0, 0) SCORE_T(ac1, 1) SCORE_T(ac2, 2) SCORE_T(ac3, 3)
  #undef SCORE_T
  #pragma unroll
  for (int off = 1; off < 16; off <<= 1){
    #pragma unroll
    for (int r = 0; r < 4; ++r){
      es0[r]  += __shfl_xor(es0[r],  off);
      es1[r]  += __shfl_xor(es1[r],  off);
      ed0a[r] += __shfl_xor(ed0a[r], off);
      ed1a[r] += __shfl_xor(ed1a[r], off);
    }
  }
  if (n16 == 0){
    #pragma unroll
    for (int r = 0; r < 4; ++r){
      int row = rowbase + q*4 + r;
      if (row < NNODES){
        atomicAdd(&esrc[row*2+0], es0[r]);
        atomicAdd(&esrc[row*2+1], es1[r]);
        atomicAdd(&edst[row*2+0], ed0a[r]);
        atomicAdd(&edst[row*2+1], ed1a[r]);
      }
    }
  }
  #pragma unroll
  for (int r = 0; r < 4; ++r){
    int row = rowbase + q * 4 + r;
    if (row >= NNODES) continue;
    int col = bn + n16;
    __hip_bfloat16* cb = Cb + (size_t)row * HPAD + col;
    if (col      < CH) cb[0]  = __float2bfloat16(ac0[r]);
    if (col + 16 < CH) cb[16] = __float2bfloat16(ac1[r]);
    if (col + 32 < CH) cb[32] = __float2bfloat16(ac2[r]);
    if (col + 48 < CH) cb[48] = __float2bfloat16(ac3[r]);
  }
}

// ---------------- fused softmax + gather for one node ----------------
__device__ __forceinline__ void attn_body(int node, char* smemc,
    const __hip_bfloat16* __restrict__ h, const float* __restrict__ esrc,
    const float* __restrict__ edst, const int* __restrict__ rowptr,
    const int* __restrict__ csr_src, const float* __restrict__ bias,
    __hip_bfloat16* __restrict__ outb, float* __restrict__ esZ, float* __restrict__ edZ){
  int tid = threadIdx.x, wave = tid >> 6, lane = tid & 63;
  int*   s_src = (int*)  smemc;
  float* s_x0  = (float*)(smemc + 1024);
  float* s_x1  = (float*)(smemc + 2048);
  float* wred0 = (float*)(smemc + 3072);
  float* wred1 = (float*)(smemc + 3088);
  float* sh    = (float*)(smemc + 3104);
  __syncthreads();   // WAR guard vs previous node's epilogue reads
  int start = rowptr[node], deg = rowptr[node+1] - start;
  float ed0 = edst[node*2+0], ed1 = edst[node*2+1];
  float sm0 = 0.f, sm1 = 0.f;
  for (int i = tid; i < deg; i += 256){
    int src = csr_src[start + i];
    float e0 = esrc[src*2+0] + ed0; e0 = e0 > 0.f ? e0 : 0.2f*e0;
    float e1 = esrc[src*2+1] + ed1; e1 = e1 > 0.f ? e1 : 0.2f*e1;
    float x0 = __expf(e0), x1 = __expf(e1);
    if (i < DCAP){ s_src[i] = src; s_x0[i] = x0; s_x1[i] = x1; }
    sm0 += x0; sm1 += x1;
  }
  for (int off = 32; off > 0; off >>= 1){
    sm0 += __shfl_xor(sm0, off);
    sm1 += __shfl_xor(sm1, off);
  }
  if (lane == 0){ wred0[wave] = sm0; wred1[wave] = sm1; }
  __syncthreads();
  float inv0 = 1.f / ((wred0[0]+wred0[1]+wred0[2]+wred0[3]) + 1e-16f);
  float inv1 = 1.f / ((wred1[0]+wred1[1]+wred1[2]+wred1[3]) + 1e-16f);
  int c0 = 4*lane;
  bool h0_0 = (c0    ) < HOUT, h0_1 = (c0 + 1) < HOUT;
  bool h0_2 = (c0 + 2) < HOUT, h0_3 = (c0 + 3) < HOUT;
  float acc0=0.f, acc1=0.f, acc2=0.f, acc3=0.f;
  #define FETCH(I, S, A0, A1) { \
    if ((I) < DCAP){ S = s_src[I]; A0 = s_x0[I]*inv0; A1 = s_x1[I]*inv1; } \
    else { S = csr_src[start + (I)]; \
      float e0 = esrc[S*2+0] + ed0; e0 = e0 > 0.f ? e0 : 0.2f*e0; \
      float e1 = esrc[S*2+1] + ed1; e1 = e1 > 0.f ? e1 : 0.2f*e1; \
      A0 = __expf(e0)*inv0; A1 = __expf(e1)*inv1; } }
  #define GATHER(S, A0, A1) { \
    uint2 d = *(const uint2*)(h + (size_t)(S) * HPAD + c0); \
    acc0 += (h0_0 ? A0 : A1) * bfbits2f(d.x & 0xffffu); \
    acc1 += (h0_1 ? A0 : A1) * bfbits2f(d.x >> 16); \
    acc2 += (h0_2 ? A0 : A1) * bfbits2f(d.y & 0xffffu); \
    acc3 += (h0_3 ? A0 : A1) * bfbits2f(d.y >> 16); }
  int i = wave;
  for (; i + 4 < deg; i += 8){
    int sA, sB; float a0A,a1A,a0B,a1B;
    FETCH(i, sA, a0A, a1A)
    FETCH(i+4, sB, a0B, a1B)
    GATHER(sA, a0A, a1A)
    GATHER(sB, a0B, a1B)
  }
  if (i < deg){
    int sA; float a0A, a1A;
    FETCH(i, sA, a0A, a1A)
    GATHER(sA, a0A, a1A)
  }
  #undef GATHER
  #undef FETCH
  float* shw = sh + wave * 256;
  *(float4*)&shw[c0] = make_float4(acc0, acc1, acc2, acc3);
  __syncthreads();
  if (tid < 62){
    int c = 4*tid;
    float4 b4 = *(const float4*)&bias[c];
    float v0 = sh[c]   + sh[256+c]   + sh[512+c]   + sh[768+c]   + b4.x;
    float v1 = sh[c+1] + sh[256+c+1] + sh[512+c+1] + sh[768+c+1] + b4.y;
    float v2 = sh[c+2] + sh[256+c+2] + sh[512+c+2] + sh[768+c+2] + b4.z;
    float v3 = sh[c+3] + sh[256+c+3] + sh[512+c+3] + sh[768+c+3] + b4.w;
    v0 = v0 > 0.f ? v0 : 0.f; v1 = v1 > 0.f ? v1 : 0.f;
    v2 = v2 > 0.f ? v2 : 0.f; v3 = v3 > 0.f ? v3 : 0.f;
    ushort4 o; o.x = f2bfbits(v0); o.y = f2bfbits(v1); o.z = f2bfbits(v2); o.w = f2bfbits(v3);
    *(ushort4*)(outb + (size_t)node * KP1 + c) = o;
  } else if (tid == 62){
    #pragma unroll
    for (int j = 0; j < 2; ++j){
      int c = 248 + j;
      float v = sh[c] + sh[256+c] + sh[512+c] + sh[768+c] + bias[c];
      v = v > 0.f ? v : 0.f;
      outb[(size_t)node * KP1 + c] = __float2bfloat16(v);
    }
  }
  if (tid < 2){
    esZ[node*2 + tid] = 0.f;
    edZ[node*2 + tid] = 0.f;
  }
}

// ---------------- head for one graph ----------------
__device__ __forceinline__ void head_body(int g, char* smemc,
    const __hip_bfloat16* __restrict__ xb, const int* __restrict__ gstart,
    const float* __restrict__ lw1, const float* __restrict__ lb1,
    const float* __restrict__ lw2, const float* __restrict__ lb2,
    const float* __restrict__ lw3, const float* __restrict__ lb3,
    const float* __restrict__ lw4, const float* __restrict__ lb4,
    float* __restrict__ out){
  int tid = threadIdx.x;
  float* gvec = (float*)smemc;
  float* m1   = (float*)(smemc + 1024);
  float* m2   = (float*)(smemc + 1824);
  float* m3   = (float*)(smemc + 2272);
  __syncthreads();
  int s = gstart[g], e = gstart[g+1];
  if (tid < CH){
    float a0=0.f,a1=0.f,a2=0.f,a3=0.f;
    int n = s;
    for (; n + 3 < e; n += 4){
      a0 += __bfloat162float(xb[(size_t)n     * KP1 + tid]);
      a1 += __bfloat162float(xb[(size_t)(n+1) * KP1 + tid]);
      a2 += __bfloat162float(xb[(size_t)(n+2) * KP1 + tid]);
      a3 += __bfloat162float(xb[(size_t)(n+3) * KP1 + tid]);
    }
    for (; n < e; ++n) a0 += __bfloat162float(xb[(size_t)n * KP1 + tid]);
    float scale = 1.f / fmaxf((float)(e - s), 1.f);
    gvec[tid] = (a0 + a1 + a2 + a3) * scale;
  }
  __syncthreads();
  if (tid < 200){
    float a0=0.f,a1=0.f,a2=0.f,a3=0.f;
    int k = 0;
    for (; k + 3 < CH; k += 4){
      a0 += gvec[k]   * lw1[(size_t)k     * 200 + tid];
      a1 += gvec[k+1] * lw1[(size_t)(k+1) * 200 + tid];
      a2 += gvec[k+2] * lw1[(size_t)(k+2) * 200 + tid];
      a3 += gvec[k+3] * lw1[(size_t)(k+3) * 200 + tid];
    }
    for (; k < CH; ++k) a0 += gvec[k] * lw1[(size_t)k * 200 + tid];
    float v = a0 + a1 + a2 + a3 + lb1[tid];
    m1[tid] = v > 0.f ? v : 0.f;
  }
  __syncthreads();
  if (tid < 100){
    float a0=0.f,a1=0.f,a2=0.f,a3=0.f;
    for (int k = 0; k + 3 < 200; k += 4){
      a0 += m1[k]   * lw2[(size_t)k     * 100 + tid];
      a1 += m1[k+1] * lw2[(size_t)(k+1) * 100 + tid];
      a2 += m1[k+2] * lw2[(size_t)(k+2) * 100 + tid];
      a3 += m1[k+3] * lw2[(size_t)(k+3) * 100 + tid];
    }
    float v = a0 + a1 + a2 + a3 + lb2[tid];
    m2[tid] = v > 0.f ? v : 0.f;
  }
  __syncthreads();
  if (tid < 100){
    float a0=0.f,a1=0.f,a2=0.f,a3=0.f;
    for (int k = 0; k + 3 < 100; k += 4){
      a0 += m2[k]   * lw3[(size_t)k     * 100 + tid];
      a1 += m2[k+1] * lw3[(size_t)(k+1) * 100 + tid];
      a2 += m2[k+2] * lw3[(size_t)(k+2) * 100 + tid];
      a3 += m2[k+3] * lw3[(size_t)(k+3) * 100 + tid];
    }
    float v = a0 + a1 + a2 + a3 + lb3[tid];
    m3[tid] = v > 0.f ? v : 0.f;
  }
  __syncthreads();
  if (tid < 29){
    float a0=0.f,a1=0.f,a2=0.f,a3=0.f;
    for (int k = 0; k + 3 < 100; k += 4){
      a0 += m3[k]   * lw4[(size_t)k     * 29 + tid];
      a1 += m3[k+1] * lw4[(size_t)(k+1) * 29 + tid];
      a2 += m3[k+2] * lw4[(size_t)(k+2) * 29 + tid];
      a3 += m3[k+3] * lw4[(size_t)(k+3) * 29 + tid];
    }
    out[(size_t)g * 29 + tid] = a0 + a1 + a2 + a3 + lb4[tid];
  }
}

// ---------------- shared preprocessing bodies ----------------
__device__ __forceinline__ void pre_body(const MegaArgs& a, int gtid, int gstr){
  for (int e = gtid; e < ETOT; e += gstr){
    int dst = (e < NEDGES) ? a.eidx[NEDGES + e] : (e - NEDGES);
    atomicAdd(&a.deg[dst], 1);
  }
  for (int n = gtid; n < NNODES; n += gstr){
    int b1 = a.batch[n];
    int b0 = (n == 0) ? -1 : a.batch[n-1];
    for (int b = b0 + 1; b <= b1; ++b) a.gstart[b] = n;
    if (n == NNODES - 1){
      for (int b = b1 + 1; b <= NGRAPH; ++b) a.gstart[b] = NNODES;
    }
  }
  for (int i = gtid; i < NNODES*336; i += gstr){
    int r = i / 336, k = i % 336;
    a.Abf0[(size_t)r * KP0 + k] = __float2bfloat16(a.x[i]);
  }
  const int T0 = 16 * KP0 * 16;
  const int T1 = 16 * KP1 * 16;
  int tot = T0 + 3*T1;
  for (int i = gtid; i < tot; i += gstr){
    const float* W; __hip_bfloat16* Wt; int K, Kp, li;
    if (i < T0)             { W = a.W0; Wt = a.Wt0; K = 336; Kp = KP0; li = i; }
    else if (i < T0 +   T1) { W = a.W1; Wt = a.Wt1; K = CH;  Kp = KP1; li = i - T0; }
    else if (i < T0 + 2*T1) { W = a.W2; Wt = a.Wt2; K = CH;  Kp = KP1; li = i - T0 - T1; }
    else                    { W = a.W3; Wt = a.Wt3; K = CH;  Kp = KP1; li = i - T0 - 2*T1; }
    int KC = Kp >> 5;
    int nt = li / (Kp * 16);
    int rem = li % (Kp * 16);
    int k = rem / 16;
    int n = rem % 16;
    int col = nt * 16 + n;
    float v = (k < K && col < CH) ? W[(size_t)k * CH + col] : 0.f;
    Wt[(((size_t)nt * KC + (k >> 5)) * 16 + n) * 32 + (k & 31)] = __float2bfloat16(v);
  }
}
__device__ __forceinline__ void fill_body(const MegaArgs& a, int gtid, int gstr){
  for (int e = gtid; e < ETOT; e += gstr){
    int dst, src;
    if (e < NEDGES){ src = a.eidx[e]; dst = a.eidx[NEDGES + e]; }
    else           { src = e - NEDGES; dst = src; }
    int pos = atomicAdd(&a.cursor[dst], 1);
    a.csr_src[a.rowptr[dst] + pos] = src;
  }
}

// ---------------- persistent cooperative mega-kernel ----------------
__global__ __launch_bounds__(256, 4) void k_mega(MegaArgs a){
  cg::grid_group grid = cg::this_grid();
  __shared__ __align__(16) char smem[7424];
  int tid = threadIdx.x;
  int gtid = blockIdx.x * 256 + tid;
  int gstr = gridDim.x * 256;

  pre_body(a, gtid, gstr);
  grid.sync();

  if (blockIdx.x == 0){
    scan256(smem, a.deg, a.rowptr);
  } else {
    for (int t = (int)blockIdx.x - 1; t < NTILE*4; t += (int)gridDim.x - 1)
      gemm_body(t % NTILE, t / NTILE, a.Abf0, a.Wt0, a.hb16, a.as0, a.ad0, a.esA, a.edA, KP0);
  }
  grid.sync();

  fill_body(a, gtid, gstr);
  grid.sync();

  for (int node = blockIdx.x; node < NNODES; node += gridDim.x)
    attn_body(node, smem, a.hb16, a.esA, a.edA, a.rowptr, a.csr_src, a.b0,
              a.Abf, a.esB, a.edB);
  grid.sync();

  const __hip_bfloat16* Wts[3] = {a.Wt1, a.Wt2, a.Wt3};
  const float* ass[3] = {a.as1, a.as2, a.as3};
  const float* ads[3] = {a.ad1, a.ad2, a.ad3};
  const float* bbs[3] = {a.b1, a.b2, a.b3};
  for (int Lm = 0; Lm < 3; ++Lm){
    float* es  = (Lm & 1) ? a.esA : a.esB;
    float* ed  = (Lm & 1) ? a.edA : a.edB;
    float* esZ = (Lm & 1) ? a.esB : a.esA;
    float* edZ = (Lm & 1) ? a.edB : a.edA;
    for (int t = blockIdx.x; t < NTILE*4; t += gridDim.x)
      gemm_body(t % NTILE, t / NTILE, a.Abf, Wts[Lm], a.hb16, ass[Lm], ads[Lm], es, ed, KP1);
    grid.sync();
    for (int node = blockIdx.x; node < NNODES; node += gridDim.x)
      attn_body(node, smem, a.hb16, es, ed, a.rowptr, a.csr_src, bbs[Lm],
                a.Abf, esZ, edZ);
    grid.sync();
  }

  for (int g = blockIdx.x; g < NGRAPH; g += gridDim.x)
    head_body(g, smem, a.Abf, a.gstart, a.lw1, a.lb1, a.lw2, a.lb2,
              a.lw3, a.lb3, a.lw4, a.lb4, a.out);
}

// ---------------- fallback standalone kernels (round-10 path, shared bodies) ----------------
__global__ void k_pre(MegaArgs a){
  pre_body(a, blockIdx.x * blockDim.x + threadIdx.x, gridDim.x * blockDim.x);
}
__global__ __launch_bounds__(256) void k_scan_s(const int* __restrict__ deg, int* __restrict__ rowptr){
  __shared__ __align__(16) char smem[128];
  scan256(smem, deg, rowptr);
}
__global__ void k_fill_s(MegaArgs a){
  fill_body(a, blockIdx.x * blockDim.x + threadIdx.x, gridDim.x * blockDim.x);
}
__global__ __launch_bounds__(256) void k_gemm_s(const __hip_bfloat16* A, const __hip_bfloat16* Wt,
    __hip_bfloat16* Cb, const float* asrc, const float* adst, float* esrc, float* edst, int Kp){
  gemm_body(blockIdx.x, blockIdx.y, A, Wt, Cb, asrc, adst, esrc, edst, Kp);
}
__global__ __launch_bounds__(256) void k_attn_s(const __hip_bfloat16* h, const float* esrc,
    const float* edst, const int* rowptr, const int* csr_src, const float* bias,
    __hip_bfloat16* outb, float* esZ, float* edZ){
  __shared__ __align__(16) char smem[7424];
  attn_body(blockIdx.x, smem, h, esrc, edst, rowptr, csr_src, bias, outb, esZ, edZ);
}
__global__ __launch_bounds__(256) void k_head_s(const __hip_bfloat16* xb, const int* gstart,
    const float* lw1, const float* lb1, const float* lw2, const float* lb2,
    const float* lw3, const float* lb3, const float* lw4, const float* lb4, float* out){
  __shared__ __align__(16) char smem[2720];
  head_body(blockIdx.x, smem, xb, gstart, lw1, lb1, lw2, lb2, lw3, lb3, lw4, lb4, out);
}

// ---------------- launch ----------------
extern "C" void kernel_launch(void* const* d_in, const int* in_sizes, int n_in,
                              void* d_out, int out_size, void* d_ws, size_t ws_size,
                              hipStream_t stream){
  char* ws = (char*)d_ws;
  size_t off = 0;
  auto alloc = [&](size_t bytes)->void*{
    void* p = ws + off;
    off = (off + bytes + 255) & ~(size_t)255;
    return p;
  };
  __hip_bfloat16* hb16 = (__hip_bfloat16*)alloc((size_t)NNODES * HPAD * 2);
  __hip_bfloat16* Abf0 = (__hip_bfloat16*)alloc((size_t)MPAD * KP0 * 2);
  __hip_bfloat16* Abf  = (__hip_bfloat16*)alloc((size_t)MPAD * KP1 * 2);
  __hip_bfloat16* Wt0  = (__hip_bfloat16*)alloc((size_t)16 * KP0 * 16 * 2);
  __hip_bfloat16* Wt1  = (__hip_bfloat16*)alloc((size_t)16 * KP1 * 16 * 2);
  __hip_bfloat16* Wt2  = (__hip_bfloat16*)alloc((size_t)16 * KP1 * 16 * 2);
  __hip_bfloat16* Wt3  = (__hip_bfloat16*)alloc((size_t)16 * KP1 * 16 * 2);
  size_t zbeg = off;
  int*   deg    = (int*)  alloc((size_t)NNODES * 4);
  int*   cursor = (int*)  alloc((size_t)NNODES * 4);
  float* esA  = (float*)alloc((size_t)NNODES * 2 * 4);
  float* edA  = (float*)alloc((size_t)NNODES * 2 * 4);
  float* esB  = (float*)alloc((size_t)NNODES * 2 * 4);
  float* edB  = (float*)alloc((size_t)NNODES * 2 * 4);
  size_t zend = off;
  int*   rowptr  = (int*)alloc((size_t)(NNODES + 1) * 4);
  int*   csr_src = (int*)alloc((size_t)ETOT * 4);
  int*   gstart  = (int*)alloc((size_t)(NGRAPH + 1) * 4);

  hipMemsetAsync(ws + zbeg, 0, zend - zbeg, stream);

  MegaArgs ma;
  ma.x = (const float*)d_in[0];
  ma.eidx = (const int*)d_in[1];
  ma.batch = (const int*)d_in[2];
  ma.W0 = (const float*)d_in[3];  ma.as0 = (const float*)d_in[4];
  ma.ad0 = (const float*)d_in[5]; ma.b0  = (const float*)d_in[6];
  ma.W1 = (const float*)d_in[7];  ma.as1 = (const float*)d_in[8];
  ma.ad1 = (const float*)d_in[9]; ma.b1  = (const float*)d_in[10];
  ma.W2 = (const float*)d_in[11]; ma.as2 = (const float*)d_in[12];
  ma.ad2 = (const float*)d_in[13]; ma.b2 = (const float*)d_in[14];
  ma.W3 = (const float*)d_in[15]; ma.as3 = (const float*)d_in[16];
  ma.ad3 = (const float*)d_in[17]; ma.b3 = (const float*)d_in[18];
  ma.lw1 = (const float*)d_in[19]; ma.lb1 = (const float*)d_in[20];
  ma.lw2 = (const float*)d_in[21]; ma.lb2 = (const float*)d_in[22];
  ma.lw3 = (const float*)d_in[23]; ma.lb3 = (const float*)d_in[24];
  ma.lw4 = (const float*)d_in[25]; ma.lb4 = (const float*)d_in[26];
  ma.hb16 = hb16; ma.Abf0 = Abf0; ma.Abf = Abf;
  ma.Wt0 = Wt0; ma.Wt1 = Wt1; ma.Wt2 = Wt2; ma.Wt3 = Wt3;
  ma.deg = deg; ma.cursor = cursor; ma.rowptr = rowptr;
  ma.csr_src = csr_src; ma.gstart = gstart;
  ma.esA = esA; ma.edA = edA; ma.esB = esB; ma.edB = edB;
  ma.out = (float*)d_out;

  // ---- try cooperative launch with occupancy-derived grid; fallback on any error ----
  bool coop_done = false;
  int occ = 0;
  hipError_t qe = hipOccupancyMaxActiveBlocksPerMultiprocessor(
      &occ, reinterpret_cast<const void*>(k_mega), 256, 0);
  if (qe == hipSuccess && occ > 0){
    long grid = (long)occ * NCUS;
    if (grid > 1024) grid = 1024;
    if (grid >= 8){
      void* kargs[] = { &ma };
      hipError_t le = hipLaunchCooperativeKernel(
          reinterpret_cast<void*>(k_mega), dim3((unsigned)grid), dim3(256), kargs, 0, stream);
      coop_done = (le == hipSuccess);
    }
  }

  if (!coop_done){
    // round-10 proven multi-kernel path (same bodies)
    k_pre  <<<(ETOT + 255)/256, 256, 0, stream>>>(ma);
    k_scan_s<<<1, 256, 0, stream>>>(deg, rowptr);
    k_fill_s<<<(ETOT + 255)/256, 256, 0, stream>>>(ma);
    const __hip_bfloat16* Wts[4] = {Wt0, Wt1, Wt2, Wt3};
    const float* ass[4] = {ma.as0, ma.as1, ma.as2, ma.as3};
    const float* ads[4] = {ma.ad0, ma.ad1, ma.ad2, ma.ad3};
    const float* bbs[4] = {ma.b0, ma.b1, ma.b2, ma.b3};
    for (int L = 0; L < 4; ++L){
      int Kp = (L == 0) ? KP0 : KP1;
      const __hip_bfloat16* Ain = (L == 0) ? Abf0 : Abf;
      float* es  = (L & 1) ? esB : esA;
      float* ed  = (L & 1) ? edB : edA;
      float* esZ = (L & 1) ? esA : esB;
      float* edZ = (L & 1) ? edA : edB;
      k_gemm_s<<<dim3(NTILE, 4), 256, 0, stream>>>(Ain, Wts[L], hb16, ass[L], ads[L], es, ed, Kp);
      k_attn_s<<<NNODES, 256, 0, stream>>>(hb16, es, ed, rowptr, csr_src, bbs[L], Abf, esZ, edZ);
    }
    k_head_s<<<NGRAPH, 256, 0, stream>>>(Abf, gstart, ma.lw1, ma.lb1, ma.lw2, ma.lb2,
                                         ma.lw3, ma.lb3, ma.lw4, ma.lb4, (float*)d_out);
  }
}

// Round 13
// 362.776 us; speedup vs baseline: 3.3401x; 3.3401x over previous
//
#include <hip/hip_runtime.h>
#include <hip/hip_bf16.h>

#define NNODES 10000
#define NEDGES 320000
#define ETOT   (NEDGES + NNODES)
#define NGRAPH 100
#define CH     250   // HEADS*OUT
#define HOUT   125
#define MPAD   10048 // 157 * 64
#define NTILE  157   // MPAD/64
#define KP0    352   // layer-0 K=336 padded
#define KP1    256   // layers 1-3 K=250 padded
#define HPAD   256   // hb16 row stride (bf16) -> 512B rows
#define DCAPW  128   // per-WAVE edge cache (deg ~Poisson(33), max<~80; fallback recompute)

typedef __attribute__((ext_vector_type(8))) short bf16x8;
typedef __attribute__((ext_vector_type(4))) float f32x4;

static __device__ __forceinline__ float bfbits2f(unsigned int u){
  union{ unsigned int i; float f; } v; v.i = u << 16; return v.f;
}
static __device__ __forceinline__ unsigned short f2bfbits(float f){
  __hip_bfloat16 b = __float2bfloat16(f);
  union{ __hip_bfloat16 b; unsigned short s; } v; v.b = b; return v.s;
}

struct Args {
  const float* x; const int* eidx; const int* batch;
  const float *W0,*W1,*W2,*W3;
  __hip_bfloat16 *hb16, *Abf0, *Abf, *Wt0, *Wt1, *Wt2, *Wt3;
  int *deg, *cursor, *rowptr, *csr_src, *gstart;
};

// ---------------- pre: deg + gstart + xconv + wconv ----------------
__global__ void k_pre(Args a){
  int gtid = blockIdx.x * blockDim.x + threadIdx.x;
  int gstr = gridDim.x * blockDim.x;
  for (int e = gtid; e < ETOT; e += gstr){
    int dst = (e < NEDGES) ? a.eidx[NEDGES + e] : (e - NEDGES);
    atomicAdd(&a.deg[dst], 1);
  }
  for (int n = gtid; n < NNODES; n += gstr){
    int b1 = a.batch[n];
    int b0 = (n == 0) ? -1 : a.batch[n-1];
    for (int b = b0 + 1; b <= b1; ++b) a.gstart[b] = n;
    if (n == NNODES - 1){
      for (int b = b1 + 1; b <= NGRAPH; ++b) a.gstart[b] = NNODES;
    }
  }
  for (int i = gtid; i < NNODES*336; i += gstr){
    int r = i / 336, k = i % 336;
    a.Abf0[(size_t)r * KP0 + k] = __float2bfloat16(a.x[i]);
  }
  const int T0 = 16 * KP0 * 16;
  const int T1 = 16 * KP1 * 16;
  int tot = T0 + 3*T1;
  for (int i = gtid; i < tot; i += gstr){
    const float* W; __hip_bfloat16* Wt; int K, Kp, li;
    if (i < T0)             { W = a.W0; Wt = a.Wt0; K = 336; Kp = KP0; li = i; }
    else if (i < T0 +   T1) { W = a.W1; Wt = a.Wt1; K = CH;  Kp = KP1; li = i - T0; }
    else if (i < T0 + 2*T1) { W = a.W2; Wt = a.Wt2; K = CH;  Kp = KP1; li = i - T0 - T1; }
    else                    { W = a.W3; Wt = a.Wt3; K = CH;  Kp = KP1; li = i - T0 - 2*T1; }
    int KC = Kp >> 5;
    int nt = li / (Kp * 16);
    int rem = li % (Kp * 16);
    int k = rem / 16;
    int n = rem % 16;
    int col = nt * 16 + n;
    float v = (k < K && col < CH) ? W[(size_t)k * CH + col] : 0.f;
    Wt[(((size_t)nt * KC + (k >> 5)) * 16 + n) * 32 + (k & 31)] = __float2bfloat16(v);
  }
}

// ---------------- exclusive scan (1 block, 256 thr) ----------------
__global__ __launch_bounds__(256) void k_scan(const int* __restrict__ deg, int* __restrict__ rowptr){
  const int CHUNK = 40;   // 256*40 = 10240 >= NNODES
  int tid = threadIdx.x;
  int base = tid * CHUNK;
  int sum = 0;
  #pragma unroll
  for (int u = 0; u < CHUNK; ++u){
    int i = base + u;
    sum += (i < NNODES) ? deg[i] : 0;
  }
  int lane = tid & 63, wv = tid >> 6;
  int v = sum;
  #pragma unroll
  for (int off = 1; off < 64; off <<= 1){
    int t = __shfl_up(v, off);
    if (lane >= off) v += t;
  }
  __shared__ int wtot[4];
  __shared__ int woff[4];
  if (lane == 63) wtot[wv] = v;
  __syncthreads();
  if (tid == 0){
    int acc = 0;
    #pragma unroll
    for (int w = 0; w < 4; ++w){ woff[w] = acc; acc += wtot[w]; }
  }
  __syncthreads();
  int run = woff[wv] + v - sum;
  #pragma unroll
  for (int u = 0; u < CHUNK; ++u){
    int i = base + u;
    if (i < NNODES){
      run += deg[i];
      rowptr[i+1] = run;
    }
  }
  if (tid == 0) rowptr[0] = 0;
}

__global__ void k_fill(Args a){
  int e = blockIdx.x * blockDim.x + threadIdx.x;
  if (e >= ETOT) return;
  int dst, src;
  if (e < NEDGES){ src = a.eidx[e]; dst = a.eidx[NEDGES + e]; }
  else           { src = e - NEDGES; dst = src; }
  int pos = atomicAdd(&a.cursor[dst], 1);
  a.csr_src[a.rowptr[dst] + pos] = src;
}

// ---------------- MFMA GEMM + fused attention scores ----------------
__global__ __launch_bounds__(256) void k_gemm(
    const __hip_bfloat16* __restrict__ A, const __hip_bfloat16* __restrict__ Wt,
    __hip_bfloat16* __restrict__ Cb, const float* __restrict__ asrc,
    const float* __restrict__ adst, float* __restrict__ esrc, float* __restrict__ edst,
    int Kp){
  int wv = threadIdx.x >> 6, lane = threadIdx.x & 63;
  int n16 = lane & 15, q = lane >> 4;
  int KC = Kp >> 5;
  int rowbase = blockIdx.x * 64 + wv * 16;
  int bn = blockIdx.y * 64;
  int nt0 = bn >> 4;
  const __hip_bfloat16* ap = A  + (size_t)(rowbase + n16) * Kp + q * 8;
  const __hip_bfloat16* bp = Wt + ((size_t)nt0 * KC * 16 + n16) * 32 + q * 8;
  f32x4 ac0 = {0.f,0.f,0.f,0.f}, ac1 = ac0, ac2 = ac0, ac3 = ac0;
  for (int kc = 0; kc < KC; ++kc){
    bf16x8 a  = *(const bf16x8*)(ap + (size_t)kc * 32);
    bf16x8 b0 = *(const bf16x8*)(bp + ((size_t)0 * KC + kc) * 512);
    bf16x8 b1 = *(const bf16x8*)(bp + ((size_t)1 * KC + kc) * 512);
    bf16x8 b2 = *(const bf16x8*)(bp + ((size_t)2 * KC + kc) * 512);
    bf16x8 b3 = *(const bf16x8*)(bp + ((size_t)3 * KC + kc) * 512);
    ac0 = __builtin_amdgcn_mfma_f32_16x16x32_bf16(a, b0, ac0, 0, 0, 0);
    ac1 = __builtin_amdgcn_mfma_f32_16x16x32_bf16(a, b1, ac1, 0, 0, 0);
    ac2 = __builtin_amdgcn_mfma_f32_16x16x32_bf16(a, b2, ac2, 0, 0, 0);
    ac3 = __builtin_amdgcn_mfma_f32_16x16x32_bf16(a, b3, ac3, 0, 0, 0);
  }
  float es0[4] = {}, es1[4] = {}, ed0a[4] = {}, ed1a[4] = {};
  #define SCORE_T(AC, T) { \
    int col = bn + (T)*16 + n16; \
    bool ok = col < CH; \
    float av = ok ? asrc[col] : 0.f; \
    float dv = ok ? adst[col] : 0.f; \
    bool hh = col >= HOUT; \
    float av0 = hh ? 0.f : av, av1 = hh ? av : 0.f; \
    float dv0 = hh ? 0.f : dv, dv1 = hh ? dv : 0.f; \
    _Pragma("unroll") \
    for (int r = 0; r < 4; ++r){ \
      es0[r] += AC[r]*av0; es1[r] += AC[r]*av1; \
      ed0a[r] += AC[r]*dv0; ed1a[r] += AC[r]*dv1; } }
  SCORE_T(ac0, 0) SCORE_T(ac1, 1) SCORE_T(ac2, 2) SCORE_T(ac3, 3)
  #undef SCORE_T
  #pragma unroll
  for (int off = 1; off < 16; off <<= 1){
    #pragma unroll
    for (int r = 0; r < 4; ++r){
      es0[r]  += __shfl_xor(es0[r],  off);
      es1[r]  += __shfl_xor(es1[r],  off);
      ed0a[r] += __shfl_xor(ed0a[r], off);
      ed1a[r] += __shfl_xor(ed1a[r], off);
    }
  }
  if (n16 == 0){
    #pragma unroll
    for (int r = 0; r < 4; ++r){
      int row = rowbase + q*4 + r;
      if (row < NNODES){
        atomicAdd(&esrc[row*2+0], es0[r]);
        atomicAdd(&esrc[row*2+1], es1[r]);
        atomicAdd(&edst[row*2+0], ed0a[r]);
        atomicAdd(&edst[row*2+1], ed1a[r]);
      }
    }
  }
  #pragma unroll
  for (int r = 0; r < 4; ++r){
    int row = rowbase + q * 4 + r;
    if (row >= NNODES) continue;
    int col = bn + n16;
    __hip_bfloat16* cb = Cb + (size_t)row * HPAD + col;
    if (col      < CH) cb[0]  = __float2bfloat16(ac0[r]);
    if (col + 16 < CH) cb[16] = __float2bfloat16(ac1[r]);
    if (col + 32 < CH) cb[32] = __float2bfloat16(ac2[r]);
    if (col + 48 < CH) cb[48] = __float2bfloat16(ac3[r]);
  }
}

// ---------------- fused softmax + gather: WAVE per node (4 nodes/block) ----------------
// Phase A: lane-strided exp(leaky(e)) -> per-wave LDS + wave-reduce sum (no block reduce).
// Phase B: lane L owns cols [4L,4L+4): one 8B load per edge, full 512B row per wave.
// No cross-wave LDS reduce; one __syncthreads for LDS RAW visibility.
__global__ __launch_bounds__(256) void k_attn(const __hip_bfloat16* __restrict__ h,
                        const float* __restrict__ esrc, const float* __restrict__ edst,
                        const int* __restrict__ rowptr, const int* __restrict__ csr_src,
                        const float* __restrict__ bias, __hip_bfloat16* __restrict__ outb,
                        float* __restrict__ esZ, float* __restrict__ edZ){
  int wv = threadIdx.x >> 6, lane = threadIdx.x & 63;
  int node = blockIdx.x * 4 + wv;    // 2500 * 4 == NNODES exactly
  __shared__ int   s_src[4][DCAPW];
  __shared__ float s_x0[4][DCAPW], s_x1[4][DCAPW];
  int start = rowptr[node], deg = rowptr[node+1] - start;
  float ed0 = edst[node*2+0], ed1 = edst[node*2+1];
  // phase A
  float sm0 = 0.f, sm1 = 0.f;
  for (int i = lane; i < deg; i += 64){
    int src = csr_src[start + i];
    float e0 = esrc[src*2+0] + ed0; e0 = e0 > 0.f ? e0 : 0.2f*e0;
    float e1 = esrc[src*2+1] + ed1; e1 = e1 > 0.f ? e1 : 0.2f*e1;
    float x0 = __expf(e0), x1 = __expf(e1);
    if (i < DCAPW){ s_src[wv][i] = src; s_x0[wv][i] = x0; s_x1[wv][i] = x1; }
    sm0 += x0; sm1 += x1;
  }
  #pragma unroll
  for (int off = 32; off > 0; off >>= 1){
    sm0 += __shfl_xor(sm0, off);
    sm1 += __shfl_xor(sm1, off);
  }
  float inv0 = 1.f / (sm0 + 1e-16f);
  float inv1 = 1.f / (sm1 + 1e-16f);
  __syncthreads();   // LDS RAW visibility within wave (and block)
  // phase B
  int c0 = 4*lane;
  bool h0_0 = (c0    ) < HOUT, h0_1 = (c0 + 1) < HOUT;
  bool h0_2 = (c0 + 2) < HOUT, h0_3 = (c0 + 3) < HOUT;
  float acc0=0.f, acc1=0.f, acc2=0.f, acc3=0.f;
  #define FETCH(I, S, A0, A1) { \
    if ((I) < DCAPW){ S = s_src[wv][I]; A0 = s_x0[wv][I]*inv0; A1 = s_x1[wv][I]*inv1; } \
    else { S = csr_src[start + (I)]; \
      float e0 = esrc[S*2+0] + ed0; e0 = e0 > 0.f ? e0 : 0.2f*e0; \
      float e1 = esrc[S*2+1] + ed1; e1 = e1 > 0.f ? e1 : 0.2f*e1; \
      A0 = __expf(e0)*inv0; A1 = __expf(e1)*inv1; } }
  #define GATHER(S, A0, A1) { \
    uint2 d = *(const uint2*)(h + (size_t)(S) * HPAD + c0); \
    acc0 += (h0_0 ? A0 : A1) * bfbits2f(d.x & 0xffffu); \
    acc1 += (h0_1 ? A0 : A1) * bfbits2f(d.x >> 16); \
    acc2 += (h0_2 ? A0 : A1) * bfbits2f(d.y & 0xffffu); \
    acc3 += (h0_3 ? A0 : A1) * bfbits2f(d.y >> 16); }
  int i = 0;
  for (; i + 1 < deg; i += 2){
    int sA, sB; float a0A,a1A,a0B,a1B;
    FETCH(i, sA, a0A, a1A)
    FETCH(i+1, sB, a0B, a1B)
    GATHER(sA, a0A, a1A)
    GATHER(sB, a0B, a1B)
  }
  if (i < deg){
    int sA; float a0A, a1A;
    FETCH(i, sA, a0A, a1A)
    GATHER(sA, a0A, a1A)
  }
  #undef GATHER
  #undef FETCH
  // epilogue: lane owns cols c0..c0+3
  if (lane < 62){
    float4 b4 = *(const float4*)&bias[c0];
    float v0 = acc0 + b4.x, v1 = acc1 + b4.y, v2 = acc2 + b4.z, v3 = acc3 + b4.w;
    v0 = v0 > 0.f ? v0 : 0.f; v1 = v1 > 0.f ? v1 : 0.f;
    v2 = v2 > 0.f ? v2 : 0.f; v3 = v3 > 0.f ? v3 : 0.f;
    ushort4 o; o.x = f2bfbits(v0); o.y = f2bfbits(v1); o.z = f2bfbits(v2); o.w = f2bfbits(v3);
    *(ushort4*)(outb + (size_t)node * KP1 + c0) = o;
  } else if (lane == 62){   // cols 248,249 (250,251 out of range)
    float v0 = acc0 + bias[248];
    float v1 = acc1 + bias[249];
    v0 = v0 > 0.f ? v0 : 0.f; v1 = v1 > 0.f ? v1 : 0.f;
    outb[(size_t)node * KP1 + 248] = __float2bfloat16(v0);
    outb[(size_t)node * KP1 + 249] = __float2bfloat16(v1);
  }
  if (lane < 2){   // prep next layer's score accumulators
    esZ[node*2 + lane] = 0.f;
    edZ[node*2 + lane] = 0.f;
  }
}

// ---------------- fused head: segmented mean pool (bf16 input) + 4-layer MLP -------------
__global__ __launch_bounds__(256) void k_head(const __hip_bfloat16* __restrict__ xb,
                        const int* __restrict__ gstart,
                        const float* __restrict__ lw1, const float* __restrict__ lb1,
                        const float* __restrict__ lw2, const float* __restrict__ lb2,
                        const float* __restrict__ lw3, const float* __restrict__ lb3,
                        const float* __restrict__ lw4, const float* __restrict__ lb4,
                        float* __restrict__ out){
  int g = blockIdx.x;
  int tid = threadIdx.x;
  int s = gstart[g], e = gstart[g+1];
  __shared__ float gvec[256];
  __shared__ float m1[200];
  __shared__ float m2[112];
  __shared__ float m3[112];
  if (tid < CH){
    float a0=0.f,a1=0.f,a2=0.f,a3=0.f;
    int n = s;
    for (; n + 3 < e; n += 4){
      a0 += __bfloat162float(xb[(size_t)n     * KP1 + tid]);
      a1 += __bfloat162float(xb[(size_t)(n+1) * KP1 + tid]);
      a2 += __bfloat162float(xb[(size_t)(n+2) * KP1 + tid]);
      a3 += __bfloat162float(xb[(size_t)(n+3) * KP1 + tid]);
    }
    for (; n < e; ++n) a0 += __bfloat162float(xb[(size_t)n * KP1 + tid]);
    float scale = 1.f / fmaxf((float)(e - s), 1.f);
    gvec[tid] = (a0 + a1 + a2 + a3) * scale;
  }
  __syncthreads();
  if (tid < 200){
    float a0=0.f,a1=0.f,a2=0.f,a3=0.f;
    int k = 0;
    for (; k + 3 < CH; k += 4){
      a0 += gvec[k]   * lw1[(size_t)k     * 200 + tid];
      a1 += gvec[k+1] * lw1[(size_t)(k+1) * 200 + tid];
      a2 += gvec[k+2] * lw1[(size_t)(k+2) * 200 + tid];
      a3 += gvec[k+3] * lw1[(size_t)(k+3) * 200 + tid];
    }
    for (; k < CH; ++k) a0 += gvec[k] * lw1[(size_t)k * 200 + tid];
    float v = a0 + a1 + a2 + a3 + lb1[tid];
    m1[tid] = v > 0.f ? v : 0.f;
  }
  __syncthreads();
  if (tid < 100){
    float a0=0.f,a1=0.f,a2=0.f,a3=0.f;
    for (int k = 0; k + 3 < 200; k += 4){
      a0 += m1[k]   * lw2[(size_t)k     * 100 + tid];
      a1 += m1[k+1] * lw2[(size_t)(k+1) * 100 + tid];
      a2 += m1[k+2] * lw2[(size_t)(k+2) * 100 + tid];
      a3 += m1[k+3] * lw2[(size_t)(k+3) * 100 + tid];
    }
    float v = a0 + a1 + a2 + a3 + lb2[tid];
    m2[tid] = v > 0.f ? v : 0.f;
  }
  __syncthreads();
  if (tid < 100){
    float a0=0.f,a1=0.f,a2=0.f,a3=0.f;
    for (int k = 0; k + 3 < 100; k += 4){
      a0 += m2[k]   * lw3[(size_t)k     * 100 + tid];
      a1 += m2[k+1] * lw3[(size_t)(k+1) * 100 + tid];
      a2 += m2[k+2] * lw3[(size_t)(k+2) * 100 + tid];
      a3 += m2[k+3] * lw3[(size_t)(k+3) * 100 + tid];
    }
    float v = a0 + a1 + a2 + a3 + lb3[tid];
    m3[tid] = v > 0.f ? v : 0.f;
  }
  __syncthreads();
  if (tid < 29){
    float a0=0.f,a1=0.f,a2=0.f,a3=0.f;
    for (int k = 0; k + 3 < 100; k += 4){
      a0 += m3[k]   * lw4[(size_t)k     * 29 + tid];
      a1 += m3[k+1] * lw4[(size_t)(k+1) * 29 + tid];
      a2 += m3[k+2] * lw4[(size_t)(k+2) * 29 + tid];
      a3 += m3[k+3] * lw4[(size_t)(k+3) * 29 + tid];
    }
    out[(size_t)g * 29 + tid] = a0 + a1 + a2 + a3 + lb4[tid];
  }
}

// ---------------- launch ----------------
extern "C" void kernel_launch(void* const* d_in, const int* in_sizes, int n_in,
                              void* d_out, int out_size, void* d_ws, size_t ws_size,
                              hipStream_t stream){
  char* ws = (char*)d_ws;
  size_t off = 0;
  auto alloc = [&](size_t bytes)->void*{
    void* p = ws + off;
    off = (off + bytes + 255) & ~(size_t)255;
    return p;
  };
  __hip_bfloat16* hb16 = (__hip_bfloat16*)alloc((size_t)NNODES * HPAD * 2);
  __hip_bfloat16* Abf0 = (__hip_bfloat16*)alloc((size_t)MPAD * KP0 * 2);
  __hip_bfloat16* Abf  = (__hip_bfloat16*)alloc((size_t)MPAD * KP1 * 2);
  __hip_bfloat16* Wt0  = (__hip_bfloat16*)alloc((size_t)16 * KP0 * 16 * 2);
  __hip_bfloat16* Wt1  = (__hip_bfloat16*)alloc((size_t)16 * KP1 * 16 * 2);
  __hip_bfloat16* Wt2  = (__hip_bfloat16*)alloc((size_t)16 * KP1 * 16 * 2);
  __hip_bfloat16* Wt3  = (__hip_bfloat16*)alloc((size_t)16 * KP1 * 16 * 2);
  size_t zbeg = off;
  int*   deg    = (int*)  alloc((size_t)NNODES * 4);
  int*   cursor = (int*)  alloc((size_t)NNODES * 4);
  float* esA  = (float*)alloc((size_t)NNODES * 2 * 4);
  float* edA  = (float*)alloc((size_t)NNODES * 2 * 4);
  float* esB  = (float*)alloc((size_t)NNODES * 2 * 4);
  float* edB  = (float*)alloc((size_t)NNODES * 2 * 4);
  size_t zend = off;
  int*   rowptr  = (int*)alloc((size_t)(NNODES + 1) * 4);
  int*   csr_src = (int*)alloc((size_t)ETOT * 4);
  int*   gstart  = (int*)alloc((size_t)(NGRAPH + 1) * 4);

  hipMemsetAsync(ws + zbeg, 0, zend - zbeg, stream);

  Args a;
  a.x = (const float*)d_in[0];
  a.eidx = (const int*)d_in[1];
  a.batch = (const int*)d_in[2];
  a.W0 = (const float*)d_in[3];  a.W1 = (const float*)d_in[7];
  a.W2 = (const float*)d_in[11]; a.W3 = (const float*)d_in[15];
  a.hb16 = hb16; a.Abf0 = Abf0; a.Abf = Abf;
  a.Wt0 = Wt0; a.Wt1 = Wt1; a.Wt2 = Wt2; a.Wt3 = Wt3;
  a.deg = deg; a.cursor = cursor; a.rowptr = rowptr;
  a.csr_src = csr_src; a.gstart = gstart;

  k_pre <<<(ETOT + 255)/256, 256, 0, stream>>>(a);
  k_scan<<<1, 256, 0, stream>>>(deg, rowptr);
  k_fill<<<(ETOT + 255)/256, 256, 0, stream>>>(a);

  const __hip_bfloat16* Wts[4] = {Wt0, Wt1, Wt2, Wt3};
  for (int L = 0; L < 4; ++L){
    const float* as_ = (const float*)d_in[4 + 4*L];
    const float* ad_ = (const float*)d_in[5 + 4*L];
    const float* bb  = (const float*)d_in[6 + 4*L];
    int Kp = (L == 0) ? KP0 : KP1;
    const __hip_bfloat16* Ain = (L == 0) ? Abf0 : Abf;
    float* es  = (L & 1) ? esB : esA;
    float* ed  = (L & 1) ? edB : edA;
    float* esZ = (L & 1) ? esA : esB;
    float* edZ = (L & 1) ? edA : edB;

    k_gemm<<<dim3(NTILE, 4), 256, 0, stream>>>(Ain, Wts[L], hb16, as_, ad_, es, ed, Kp);
    k_attn<<<NNODES/4, 256, 0, stream>>>(hb16, es, ed, rowptr, csr_src, bb, Abf, esZ, edZ);
  }

  k_head<<<NGRAPH, 256, 0, stream>>>(Abf, gstart,
      (const float*)d_in[19], (const float*)d_in[20],
      (const float*)d_in[21], (const float*)d_in[22],
      (const float*)d_in[23], (const float*)d_in[24],
      (const float*)d_in[25], (const float*)d_in[26],
      (float*)d_out);
}

// Round 14
// 316.143 us; speedup vs baseline: 3.8328x; 1.1475x over previous
//
#include <hip/hip_runtime.h>
#include <hip/hip_bf16.h>

#define NNODES 10000
#define NEDGES 320000
#define ETOT   (NEDGES + NNODES)
#define NGRAPH 100
#define CH     250   // HEADS*OUT
#define HOUT   125
#define MPAD   10048 // 157 * 64
#define NTILE  157   // MPAD/64
#define KP0    352   // layer-0 K=336 padded
#define KP1    256   // layers 1-3 K=250 padded
#define HPAD   256   // hb16 row stride (bf16) -> 512B rows
#define ECAP   128   // bucket capacity per node: deg ~ 1+Poisson(32), +16 sigma; guarded
#define DCAPW  128   // per-wave LDS edge cache (>= max deg in practice)

typedef __attribute__((ext_vector_type(8))) short bf16x8;
typedef __attribute__((ext_vector_type(4))) float f32x4;

static __device__ __forceinline__ float bfbits2f(unsigned int u){
  union{ unsigned int i; float f; } v; v.i = u << 16; return v.f;
}
static __device__ __forceinline__ unsigned short f2bfbits(float f){
  __hip_bfloat16 b = __float2bfloat16(f);
  union{ __hip_bfloat16 b; unsigned short s; } v; v.b = b; return v.s;
}

struct Args {
  const float* x; const int* eidx; const int* batch;
  const float *W0,*W1,*W2,*W3;
  __hip_bfloat16 *hb16, *Abf0, *Abf, *Wt0, *Wt1, *Wt2, *Wt3;
  int *cursor, *bucket, *gstart;
};

// ---------------- pre: bucketed edge placement + gstart + xconv + wconv ----------------
// Counting-sort CSR replaced by fixed-capacity buckets: one atomicAdd both counts
// (cursor ends = deg) and places. No scan, no second pass. (R14: kills k_scan+k_fill.)
__global__ void k_pre(Args a){
  int gtid = blockIdx.x * blockDim.x + threadIdx.x;
  int gstr = gridDim.x * blockDim.x;
  for (int e = gtid; e < ETOT; e += gstr){
    int dst, src;
    if (e < NEDGES){ src = a.eidx[e]; dst = a.eidx[NEDGES + e]; }
    else           { src = e - NEDGES; dst = src; }
    int pos = atomicAdd(&a.cursor[dst], 1);
    if (pos < ECAP) a.bucket[(size_t)dst * ECAP + pos] = src;
  }
  for (int n = gtid; n < NNODES; n += gstr){
    int b1 = a.batch[n];
    int b0 = (n == 0) ? -1 : a.batch[n-1];
    for (int b = b0 + 1; b <= b1; ++b) a.gstart[b] = n;
    if (n == NNODES - 1){
      for (int b = b1 + 1; b <= NGRAPH; ++b) a.gstart[b] = NNODES;
    }
  }
  for (int i = gtid; i < NNODES*336; i += gstr){
    int r = i / 336, k = i % 336;
    a.Abf0[(size_t)r * KP0 + k] = __float2bfloat16(a.x[i]);
  }
  const int T0 = 16 * KP0 * 16;
  const int T1 = 16 * KP1 * 16;
  int tot = T0 + 3*T1;
  for (int i = gtid; i < tot; i += gstr){
    const float* W; __hip_bfloat16* Wt; int K, Kp, li;
    if (i < T0)             { W = a.W0; Wt = a.Wt0; K = 336; Kp = KP0; li = i; }
    else if (i < T0 +   T1) { W = a.W1; Wt = a.Wt1; K = CH;  Kp = KP1; li = i - T0; }
    else if (i < T0 + 2*T1) { W = a.W2; Wt = a.Wt2; K = CH;  Kp = KP1; li = i - T0 - T1; }
    else                    { W = a.W3; Wt = a.Wt3; K = CH;  Kp = KP1; li = i - T0 - 2*T1; }
    int KC = Kp >> 5;
    int nt = li / (Kp * 16);
    int rem = li % (Kp * 16);
    int k = rem / 16;
    int n = rem % 16;
    int col = nt * 16 + n;
    float v = (k < K && col < CH) ? W[(size_t)k * CH + col] : 0.f;
    Wt[(((size_t)nt * KC + (k >> 5)) * 16 + n) * 32 + (k & 31)] = __float2bfloat16(v);
  }
}

// ---------------- MFMA GEMM + fused attention scores ----------------
__global__ __launch_bounds__(256) void k_gemm(
    const __hip_bfloat16* __restrict__ A, const __hip_bfloat16* __restrict__ Wt,
    __hip_bfloat16* __restrict__ Cb, const float* __restrict__ asrc,
    const float* __restrict__ adst, float* __restrict__ esrc, float* __restrict__ edst,
    int Kp){
  int wv = threadIdx.x >> 6, lane = threadIdx.x & 63;
  int n16 = lane & 15, q = lane >> 4;
  int KC = Kp >> 5;
  int rowbase = blockIdx.x * 64 + wv * 16;
  int bn = blockIdx.y * 64;
  int nt0 = bn >> 4;
  const __hip_bfloat16* ap = A  + (size_t)(rowbase + n16) * Kp + q * 8;
  const __hip_bfloat16* bp = Wt + ((size_t)nt0 * KC * 16 + n16) * 32 + q * 8;
  f32x4 ac0 = {0.f,0.f,0.f,0.f}, ac1 = ac0, ac2 = ac0, ac3 = ac0;
  for (int kc = 0; kc < KC; ++kc){
    bf16x8 a  = *(const bf16x8*)(ap + (size_t)kc * 32);
    bf16x8 b0 = *(const bf16x8*)(bp + ((size_t)0 * KC + kc) * 512);
    bf16x8 b1 = *(const bf16x8*)(bp + ((size_t)1 * KC + kc) * 512);
    bf16x8 b2 = *(const bf16x8*)(bp + ((size_t)2 * KC + kc) * 512);
    bf16x8 b3 = *(const bf16x8*)(bp + ((size_t)3 * KC + kc) * 512);
    ac0 = __builtin_amdgcn_mfma_f32_16x16x32_bf16(a, b0, ac0, 0, 0, 0);
    ac1 = __builtin_amdgcn_mfma_f32_16x16x32_bf16(a, b1, ac1, 0, 0, 0);
    ac2 = __builtin_amdgcn_mfma_f32_16x16x32_bf16(a, b2, ac2, 0, 0, 0);
    ac3 = __builtin_amdgcn_mfma_f32_16x16x32_bf16(a, b3, ac3, 0, 0, 0);
  }
  float es0[4] = {}, es1[4] = {}, ed0a[4] = {}, ed1a[4] = {};
  #define SCORE_T(AC, T) { \
    int col = bn + (T)*16 + n16; \
    bool ok = col < CH; \
    float av = ok ? asrc[col] : 0.f; \
    float dv = ok ? adst[col] : 0.f; \
    bool hh = col >= HOUT; \
    float av0 = hh ? 0.f : av, av1 = hh ? av : 0.f; \
    float dv0 = hh ? 0.f : dv, dv1 = hh ? dv : 0.f; \
    _Pragma("unroll") \
    for (int r = 0; r < 4; ++r){ \
      es0[r] += AC[r]*av0; es1[r] += AC[r]*av1; \
      ed0a[r] += AC[r]*dv0; ed1a[r] += AC[r]*dv1; } }
  SCORE_T(ac0, 0) SCORE_T(ac1, 1) SCORE_T(ac2, 2) SCORE_T(ac3, 3)
  #undef SCORE_T
  #pragma unroll
  for (int off = 1; off < 16; off <<= 1){
    #pragma unroll
    for (int r = 0; r < 4; ++r){
      es0[r]  += __shfl_xor(es0[r],  off);
      es1[r]  += __shfl_xor(es1[r],  off);
      ed0a[r] += __shfl_xor(ed0a[r], off);
      ed1a[r] += __shfl_xor(ed1a[r], off);
    }
  }
  if (n16 == 0){
    #pragma unroll
    for (int r = 0; r < 4; ++r){
      int row = rowbase + q*4 + r;
      if (row < NNODES){
        atomicAdd(&esrc[row*2+0], es0[r]);
        atomicAdd(&esrc[row*2+1], es1[r]);
        atomicAdd(&edst[row*2+0], ed0a[r]);
        atomicAdd(&edst[row*2+1], ed1a[r]);
      }
    }
  }
  #pragma unroll
  for (int r = 0; r < 4; ++r){
    int row = rowbase + q * 4 + r;
    if (row >= NNODES) continue;
    int col = bn + n16;
    __hip_bfloat16* cb = Cb + (size_t)row * HPAD + col;
    if (col      < CH) cb[0]  = __float2bfloat16(ac0[r]);
    if (col + 16 < CH) cb[16] = __float2bfloat16(ac1[r]);
    if (col + 32 < CH) cb[32] = __float2bfloat16(ac2[r]);
    if (col + 48 < CH) cb[48] = __float2bfloat16(ac3[r]);
  }
}

// ---------------- fused softmax + gather: wave per node, bucketed edges ----------------
__global__ __launch_bounds__(256) void k_attn(const __hip_bfloat16* __restrict__ h,
                        const float* __restrict__ esrc, const float* __restrict__ edst,
                        const int* __restrict__ degv, const int* __restrict__ bucket,
                        const float* __restrict__ bias, __hip_bfloat16* __restrict__ outb,
                        float* __restrict__ esZ, float* __restrict__ edZ){
  int wv = threadIdx.x >> 6, lane = threadIdx.x & 63;
  int node = blockIdx.x * 4 + wv;    // 2500 * 4 == NNODES exactly
  __shared__ int   s_src[4][DCAPW];
  __shared__ float s_x0[4][DCAPW], s_x1[4][DCAPW];
  int deg = degv[node]; if (deg > ECAP) deg = ECAP;
  const int* __restrict__ eb = bucket + (size_t)node * ECAP;
  float ed0 = edst[node*2+0], ed1 = edst[node*2+1];
  // phase A: exp(leaky(e)) -> LDS + wave sum
  float sm0 = 0.f, sm1 = 0.f;
  for (int i = lane; i < deg; i += 64){
    int src = eb[i];
    float e0 = esrc[src*2+0] + ed0; e0 = e0 > 0.f ? e0 : 0.2f*e0;
    float e1 = esrc[src*2+1] + ed1; e1 = e1 > 0.f ? e1 : 0.2f*e1;
    float x0 = __expf(e0), x1 = __expf(e1);
    if (i < DCAPW){ s_src[wv][i] = src; s_x0[wv][i] = x0; s_x1[wv][i] = x1; }
    sm0 += x0; sm1 += x1;
  }
  #pragma unroll
  for (int off = 32; off > 0; off >>= 1){
    sm0 += __shfl_xor(sm0, off);
    sm1 += __shfl_xor(sm1, off);
  }
  float inv0 = 1.f / (sm0 + 1e-16f);
  float inv1 = 1.f / (sm1 + 1e-16f);
  __syncthreads();   // LDS RAW visibility
  // phase B: lane owns cols [4L,4L+4): one 8B load per edge
  int c0 = 4*lane;
  bool h0_0 = (c0    ) < HOUT, h0_1 = (c0 + 1) < HOUT;
  bool h0_2 = (c0 + 2) < HOUT, h0_3 = (c0 + 3) < HOUT;
  float acc0=0.f, acc1=0.f, acc2=0.f, acc3=0.f;
  #define FETCH(I, S, A0, A1) { \
    if ((I) < DCAPW){ S = s_src[wv][I]; A0 = s_x0[wv][I]*inv0; A1 = s_x1[wv][I]*inv1; } \
    else { S = eb[I]; \
      float e0 = esrc[S*2+0] + ed0; e0 = e0 > 0.f ? e0 : 0.2f*e0; \
      float e1 = esrc[S*2+1] + ed1; e1 = e1 > 0.f ? e1 : 0.2f*e1; \
      A0 = __expf(e0)*inv0; A1 = __expf(e1)*inv1; } }
  #define GATHER(S, A0, A1) { \
    uint2 d = *(const uint2*)(h + (size_t)(S) * HPAD + c0); \
    acc0 += (h0_0 ? A0 : A1) * bfbits2f(d.x & 0xffffu); \
    acc1 += (h0_1 ? A0 : A1) * bfbits2f(d.x >> 16); \
    acc2 += (h0_2 ? A0 : A1) * bfbits2f(d.y & 0xffffu); \
    acc3 += (h0_3 ? A0 : A1) * bfbits2f(d.y >> 16); }
  int i = 0;
  for (; i + 1 < deg; i += 2){
    int sA, sB; float a0A,a1A,a0B,a1B;
    FETCH(i, sA, a0A, a1A)
    FETCH(i+1, sB, a0B, a1B)
    GATHER(sA, a0A, a1A)
    GATHER(sB, a0B, a1B)
  }
  if (i < deg){
    int sA; float a0A, a1A;
    FETCH(i, sA, a0A, a1A)
    GATHER(sA, a0A, a1A)
  }
  #undef GATHER
  #undef FETCH
  if (lane < 62){
    float4 b4 = *(const float4*)&bias[c0];
    float v0 = acc0 + b4.x, v1 = acc1 + b4.y, v2 = acc2 + b4.z, v3 = acc3 + b4.w;
    v0 = v0 > 0.f ? v0 : 0.f; v1 = v1 > 0.f ? v1 : 0.f;
    v2 = v2 > 0.f ? v2 : 0.f; v3 = v3 > 0.f ? v3 : 0.f;
    ushort4 o; o.x = f2bfbits(v0); o.y = f2bfbits(v1); o.z = f2bfbits(v2); o.w = f2bfbits(v3);
    *(ushort4*)(outb + (size_t)node * KP1 + c0) = o;
  } else if (lane == 62){
    float v0 = acc0 + bias[248];
    float v1 = acc1 + bias[249];
    v0 = v0 > 0.f ? v0 : 0.f; v1 = v1 > 0.f ? v1 : 0.f;
    outb[(size_t)node * KP1 + 248] = __float2bfloat16(v0);
    outb[(size_t)node * KP1 + 249] = __float2bfloat16(v1);
  }
  if (lane < 2){   // prep next layer's score accumulators
    esZ[node*2 + lane] = 0.f;
    edZ[node*2 + lane] = 0.f;
  }
}

// ---------------- fused head: segmented mean pool (bf16 input) + 4-layer MLP -------------
__global__ __launch_bounds__(256) void k_head(const __hip_bfloat16* __restrict__ xb,
                        const int* __restrict__ gstart,
                        const float* __restrict__ lw1, const float* __restrict__ lb1,
                        const float* __restrict__ lw2, const float* __restrict__ lb2,
                        const float* __restrict__ lw3, const float* __restrict__ lb3,
                        const float* __restrict__ lw4, const float* __restrict__ lb4,
                        float* __restrict__ out){
  int g = blockIdx.x;
  int tid = threadIdx.x;
  int s = gstart[g], e = gstart[g+1];
  __shared__ float gvec[256];
  __shared__ float m1[200];
  __shared__ float m2[112];
  __shared__ float m3[112];
  if (tid < CH){
    float a0=0.f,a1=0.f,a2=0.f,a3=0.f;
    int n = s;
    for (; n + 3 < e; n += 4){
      a0 += __bfloat162float(xb[(size_t)n     * KP1 + tid]);
      a1 += __bfloat162float(xb[(size_t)(n+1) * KP1 + tid]);
      a2 += __bfloat162float(xb[(size_t)(n+2) * KP1 + tid]);
      a3 += __bfloat162float(xb[(size_t)(n+3) * KP1 + tid]);
    }
    for (; n < e; ++n) a0 += __bfloat162float(xb[(size_t)n * KP1 + tid]);
    float scale = 1.f / fmaxf((float)(e - s), 1.f);
    gvec[tid] = (a0 + a1 + a2 + a3) * scale;
  }
  __syncthreads();
  if (tid < 200){
    float a0=0.f,a1=0.f,a2=0.f,a3=0.f;
    int k = 0;
    for (; k + 3 < CH; k += 4){
      a0 += gvec[k]   * lw1[(size_t)k     * 200 + tid];
      a1 += gvec[k+1] * lw1[(size_t)(k+1) * 200 + tid];
      a2 += gvec[k+2] * lw1[(size_t)(k+2) * 200 + tid];
      a3 += gvec[k+3] * lw1[(size_t)(k+3) * 200 + tid];
    }
    for (; k < CH; ++k) a0 += gvec[k] * lw1[(size_t)k * 200 + tid];
    float v = a0 + a1 + a2 + a3 + lb1[tid];
    m1[tid] = v > 0.f ? v : 0.f;
  }
  __syncthreads();
  if (tid < 100){
    float a0=0.f,a1=0.f,a2=0.f,a3=0.f;
    for (int k = 0; k + 3 < 200; k += 4){
      a0 += m1[k]   * lw2[(size_t)k     * 100 + tid];
      a1 += m1[k+1] * lw2[(size_t)(k+1) * 100 + tid];
      a2 += m1[k+2] * lw2[(size_t)(k+2) * 100 + tid];
      a3 += m1[k+3] * lw2[(size_t)(k+3) * 100 + tid];
    }
    float v = a0 + a1 + a2 + a3 + lb2[tid];
    m2[tid] = v > 0.f ? v : 0.f;
  }
  __syncthreads();
  if (tid < 100){
    float a0=0.f,a1=0.f,a2=0.f,a3=0.f;
    for (int k = 0; k + 3 < 100; k += 4){
      a0 += m2[k]   * lw3[(size_t)k     * 100 + tid];
      a1 += m2[k+1] * lw3[(size_t)(k+1) * 100 + tid];
      a2 += m2[k+2] * lw3[(size_t)(k+2) * 100 + tid];
      a3 += m2[k+3] * lw3[(size_t)(k+3) * 100 + tid];
    }
    float v = a0 + a1 + a2 + a3 + lb3[tid];
    m3[tid] = v > 0.f ? v : 0.f;
  }
  __syncthreads();
  if (tid < 29){
    float a0=0.f,a1=0.f,a2=0.f,a3=0.f;
    for (int k = 0; k + 3 < 100; k += 4){
      a0 += m3[k]   * lw4[(size_t)k     * 29 + tid];
      a1 += m3[k+1] * lw4[(size_t)(k+1) * 29 + tid];
      a2 += m3[k+2] * lw4[(size_t)(k+2) * 29 + tid];
      a3 += m3[k+3] * lw4[(size_t)(k+3) * 29 + tid];
    }
    out[(size_t)g * 29 + tid] = a0 + a1 + a2 + a3 + lb4[tid];
  }
}

// ---------------- launch ----------------
extern "C" void kernel_launch(void* const* d_in, const int* in_sizes, int n_in,
                              void* d_out, int out_size, void* d_ws, size_t ws_size,
                              hipStream_t stream){
  char* ws = (char*)d_ws;
  size_t off = 0;
  auto alloc = [&](size_t bytes)->void*{
    void* p = ws + off;
    off = (off + bytes + 255) & ~(size_t)255;
    return p;
  };
  __hip_bfloat16* hb16 = (__hip_bfloat16*)alloc((size_t)NNODES * HPAD * 2);
  __hip_bfloat16* Abf0 = (__hip_bfloat16*)alloc((size_t)MPAD * KP0 * 2);
  __hip_bfloat16* Abf  = (__hip_bfloat16*)alloc((size_t)MPAD * KP1 * 2);
  __hip_bfloat16* Wt0  = (__hip_bfloat16*)alloc((size_t)16 * KP0 * 16 * 2);
  __hip_bfloat16* Wt1  = (__hip_bfloat16*)alloc((size_t)16 * KP1 * 16 * 2);
  __hip_bfloat16* Wt2  = (__hip_bfloat16*)alloc((size_t)16 * KP1 * 16 * 2);
  __hip_bfloat16* Wt3  = (__hip_bfloat16*)alloc((size_t)16 * KP1 * 16 * 2);
  size_t zbeg = off;
  int*   cursor = (int*)  alloc((size_t)NNODES * 4);      // doubles as deg
  float* esA  = (float*)alloc((size_t)NNODES * 2 * 4);
  float* edA  = (float*)alloc((size_t)NNODES * 2 * 4);
  size_t zend = off;
  float* esB  = (float*)alloc((size_t)NNODES * 2 * 4);    // zeroed by attn L0
  float* edB  = (float*)alloc((size_t)NNODES * 2 * 4);
  int*   bucket = (int*)alloc((size_t)NNODES * ECAP * 4);
  int*   gstart = (int*)alloc((size_t)(NGRAPH + 1) * 4);

  hipMemsetAsync(ws + zbeg, 0, zend - zbeg, stream);

  Args a;
  a.x = (const float*)d_in[0];
  a.eidx = (const int*)d_in[1];
  a.batch = (const int*)d_in[2];
  a.W0 = (const float*)d_in[3];  a.W1 = (const float*)d_in[7];
  a.W2 = (const float*)d_in[11]; a.W3 = (const float*)d_in[15];
  a.hb16 = hb16; a.Abf0 = Abf0; a.Abf = Abf;
  a.Wt0 = Wt0; a.Wt1 = Wt1; a.Wt2 = Wt2; a.Wt3 = Wt3;
  a.cursor = cursor; a.bucket = bucket; a.gstart = gstart;

  k_pre<<<(ETOT + 255)/256, 256, 0, stream>>>(a);

  const __hip_bfloat16* Wts[4] = {Wt0, Wt1, Wt2, Wt3};
  for (int L = 0; L < 4; ++L){
    const float* as_ = (const float*)d_in[4 + 4*L];
    const float* ad_ = (const float*)d_in[5 + 4*L];
    const float* bb  = (const float*)d_in[6 + 4*L];
    int Kp = (L == 0) ? KP0 : KP1;
    const __hip_bfloat16* Ain = (L == 0) ? Abf0 : Abf;
    float* es  = (L & 1) ? esB : esA;
    float* ed  = (L & 1) ? edB : edA;
    float* esZ = (L & 1) ? esA : esB;
    float* edZ = (L & 1) ? edA : edB;

    k_gemm<<<dim3(NTILE, 4), 256, 0, stream>>>(Ain, Wts[L], hb16, as_, ad_, es, ed, Kp);
    k_attn<<<NNODES/4, 256, 0, stream>>>(hb16, es, ed, cursor, bucket, bb, Abf, esZ, edZ);
  }

  k_head<<<NGRAPH, 256, 0, stream>>>(Abf, gstart,
      (const float*)d_in[19], (const float*)d_in[20],
      (const float*)d_in[21], (const float*)d_in[22],
      (const float*)d_in[23], (const float*)d_in[24],
      (const float*)d_in[25], (const float*)d_in[26],
      (float*)d_out);
}